// Round 3
// baseline (1930.387 us; speedup 1.0000x reference)
//
#include <hip/hip_runtime.h>
#include <math.h>

// Problem constants (reference file)
#define NPTS   500000
#define CIN    16
#define COUT   64
#define PE     32
#define GRID_H 256
#define GRID_W 256
#define NCELL  (GRID_H * GRID_W)   // 65536

#define PT_THREADS 512
#define PT_BLOCKS  ((NPTS + PT_THREADS - 1) / PT_THREADS)   // 977

#define NK2_1    104                 // 208 rows of W1 -> 104 k-pairs
#define NK2_2    32                  // 64 rows of W2  -> 32 k-pairs
#define W1_HALF2 (NK2_1 * COUT)      // 6656 half2
#define W2_HALF2 (NK2_2 * COUT)      // 2048 half2

typedef _Float16 h2v __attribute__((ext_vector_type(2)));
typedef _Float16 h8v __attribute__((ext_vector_type(8)));

#if __has_builtin(__builtin_amdgcn_fdot2)
#define FDOT2(a, b, c) __builtin_amdgcn_fdot2((a), (b), (c), false)
#else
__device__ __forceinline__ float FDOT2(h2v a, h2v b, float c) {
    return c + (float)a[0] * (float)b[0] + (float)a[1] * (float)b[1];
}
#endif

// One k-pair row (64 channels, 128 halfs = 256 B) from LDS, uniform address
// -> 16 broadcast ds_read_b128, accumulated into acc[0..63] (fp32) via dot2.
#define DOT_ROW(half_off, xp, acc)                                  \
    {                                                               \
        const h8v* row_ = (const h8v*)(Wl + (half_off));            \
        _Pragma("unroll")                                           \
        for (int r_ = 0; r_ < 16; ++r_) {                           \
            h8v w_ = row_[r_];                                      \
            h2v wA_; wA_[0] = w_[0]; wA_[1] = w_[1];                \
            h2v wB_; wB_[0] = w_[2]; wB_[1] = w_[3];                \
            h2v wC_; wC_[0] = w_[4]; wC_[1] = w_[5];                \
            h2v wD_; wD_[0] = w_[6]; wD_[1] = w_[7];                \
            acc[4 * r_ + 0] = FDOT2(xp, wA_, acc[4 * r_ + 0]);      \
            acc[4 * r_ + 1] = FDOT2(xp, wB_, acc[4 * r_ + 1]);      \
            acc[4 * r_ + 2] = FDOT2(xp, wC_, acc[4 * r_ + 2]);      \
            acc[4 * r_ + 3] = FDOT2(xp, wD_, acc[4 * r_ + 3]);      \
        }                                                           \
    }

__device__ __forceinline__ int cell_index(float v) {
    float nf = fminf(fmaxf((v + 1.0f) * 0.5f, 0.0f), 1.0f);
    int i = (int)floorf(nf * 256.0f);
    return i > 255 ? 255 : i;
}

__global__ __launch_bounds__(PT_THREADS, 4)
void point_kernel(const float* __restrict__ pos,
                  const float* __restrict__ feats,
                  const float* __restrict__ W1,
                  const float* __restrict__ b1,
                  const float* __restrict__ ln_g,
                  const float* __restrict__ ln_b,
                  const float* __restrict__ W2,
                  const float* __restrict__ b2,
                  const int*   __restrict__ ax1p,
                  const int*   __restrict__ ax2p,
                  float* __restrict__ sums,   // [COUT][NCELL] == d_out
                  float* __restrict__ cnt)    // [NCELL]
{
    // Weights as fp16 k-pair-packed half2: W1P[k2][c] = (W[2k2][c], W[2k2+1][c])
    __shared__ __align__(16) _Float16 Wl[(W1_HALF2 + W2_HALF2) * 2]; // 34.8 KB

    for (int i = threadIdx.x; i < W1_HALF2 + W2_HALF2; i += PT_THREADS) {
        float a, b;
        if (i < W1_HALF2) {
            int base = ((i >> 6) << 7) | (i & 63);   // k2*128 + c
            a = W1[base]; b = W1[base + 64];
        } else {
            int j = i - W1_HALF2;
            int base = ((j >> 6) << 7) | (j & 63);
            a = W2[base]; b = W2[base + 64];
        }
        h2v p; p[0] = (_Float16)a; p[1] = (_Float16)b;
        ((h2v*)Wl)[i] = p;
    }
    __syncthreads();

    const int gid    = blockIdx.x * PT_THREADS + threadIdx.x;
    const bool valid = (gid < NPTS);
    const int p      = valid ? gid : (NPTS - 1);   // clamp: body stays uniform

    const float px = pos[p * 3 + 0];
    const float py = pos[p * 3 + 1];
    const float pz = pos[p * 3 + 2];

    const float4* fvp = (const float4*)(feats + (size_t)p * CIN);
    const float4 f0 = fvp[0], f1 = fvp[1], f2 = fvp[2], f3 = fvp[3];

    // ---- GEMM1: h = [feats | PE(pos)] @ W1 + b1  (dot2, fp32 accum) -------
    float h[COUT];
    #pragma unroll
    for (int c = 0; c < COUT; ++c) h[c] = b1[c];

    {   // feature rows: 8 k-pairs (rows 0..15)
        h2v xp;
        xp[0] = (_Float16)f0.x; xp[1] = (_Float16)f0.y; DOT_ROW(0 * 128, xp, h);
        xp[0] = (_Float16)f0.z; xp[1] = (_Float16)f0.w; DOT_ROW(1 * 128, xp, h);
        xp[0] = (_Float16)f1.x; xp[1] = (_Float16)f1.y; DOT_ROW(2 * 128, xp, h);
        xp[0] = (_Float16)f1.z; xp[1] = (_Float16)f1.w; DOT_ROW(3 * 128, xp, h);
        xp[0] = (_Float16)f2.x; xp[1] = (_Float16)f2.y; DOT_ROW(4 * 128, xp, h);
        xp[0] = (_Float16)f2.z; xp[1] = (_Float16)f2.w; DOT_ROW(5 * 128, xp, h);
        xp[0] = (_Float16)f3.x; xp[1] = (_Float16)f3.y; DOT_ROW(6 * 128, xp, h);
        xp[0] = (_Float16)f3.z; xp[1] = (_Float16)f3.w; DOT_ROW(7 * 128, xp, h);
    }

    // PE rows: dim d -> sin k-pairs at k2 = 8+32d+j, cos at k2 = 8+32d+16+j
    // angle(k) = pos_d * (pi/2) * 2^(k/32); pair step = 2^(1/32), j step = 2^(1/16)
    #pragma unroll 1
    for (int d = 0; d < 3; ++d) {
        float pv = (d == 0) ? px : ((d == 1) ? py : pz);
        int  k2b = 8 + 32 * d;
        float a  = pv * 1.57079632679489662f;
        #pragma unroll 1
        for (int j = 0; j < 16; ++j) {
            float s0 = __sinf(a);
            float s1 = __sinf(a * 1.0218971486541166f);
            h2v xp; xp[0] = (_Float16)s0; xp[1] = (_Float16)s1;
            DOT_ROW((k2b + j) * 128, xp, h);
            a *= 1.0442737824274138f;   // 2^(1/16)
        }
        a = pv * 1.57079632679489662f;
        #pragma unroll 1
        for (int j = 0; j < 16; ++j) {
            float c0 = __cosf(a);
            float c1 = __cosf(a * 1.0218971486541166f);
            h2v xp; xp[0] = (_Float16)c0; xp[1] = (_Float16)c1;
            DOT_ROW((k2b + 16 + j) * 128, xp, h);
            a *= 1.0442737824274138f;
        }
    }

    // ---- LayerNorm --------------------------------------------------------
    float s1 = 0.0f, s2 = 0.0f;
    #pragma unroll
    for (int c = 0; c < COUT; ++c) { s1 += h[c]; s2 += h[c] * h[c]; }
    float mu   = s1 * (1.0f / COUT);
    float var  = s2 * (1.0f / COUT) - mu * mu;
    float rstd = __builtin_amdgcn_rsqf(var + 1e-5f);

    // ---- GELU (tanh approx) -> packed fp16 pairs (channels 2c,2c+1) -------
    h2v gh[NK2_2];
    #pragma unroll
    for (int c2 = 0; c2 < NK2_2; ++c2) {
        float xa = (h[2 * c2]     - mu) * rstd * ln_g[2 * c2]     + ln_b[2 * c2];
        float xb = (h[2 * c2 + 1] - mu) * rstd * ln_g[2 * c2 + 1] + ln_b[2 * c2 + 1];
        float ua = xa * (0.7978845608028654f + 0.0356774081363001f * xa * xa);
        float ub = xb * (0.7978845608028654f + 0.0356774081363001f * xb * xb);
        float ea = __expf(2.0f * ua);
        float eb = __expf(2.0f * ub);
        float ta = 1.0f - 2.0f * __builtin_amdgcn_rcpf(ea + 1.0f);
        float tb = 1.0f - 2.0f * __builtin_amdgcn_rcpf(eb + 1.0f);
        h2v g2;
        g2[0] = (_Float16)(0.5f * xa * (1.0f + ta));
        g2[1] = (_Float16)(0.5f * xb * (1.0f + tb));
        gh[c2] = g2;
    }

    // ---- GEMM2: feat = g @ W2 + b2  (fully unrolled, static gh index) -----
    float f[COUT];
    #pragma unroll
    for (int c = 0; c < COUT; ++c) f[c] = b2[c];
    #pragma unroll
    for (int j2 = 0; j2 < NK2_2; ++j2) {
        DOT_ROW(W1_HALF2 * 2 + j2 * 128, gh[j2], f);
    }

    // ---- scatter-add into [c][cell] grid ----------------------------------
    const int ax1 = ax1p[0], ax2 = ax2p[0];
    float pa1 = (ax1 == 0) ? px : ((ax1 == 1) ? py : pz);
    float pa2 = (ax2 == 0) ? px : ((ax2 == 1) ? py : pz);
    int flat = cell_index(pa1) * GRID_W + cell_index(pa2);

    if (valid) {
        #pragma unroll
        for (int c = 0; c < COUT; ++c)
            unsafeAtomicAdd(&sums[c * NCELL + flat], f[c]);
        unsafeAtomicAdd(&cnt[flat], 1.0f);
    }
}

__global__ void finalize_kernel(float* __restrict__ out,
                                const float* __restrict__ cnt)
{
    int t = blockIdx.x * blockDim.x + threadIdx.x;   // grid sized exactly
    float c = cnt[t & (NCELL - 1)];
    out[t] = out[t] / fmaxf(c, 1.0f);
}

extern "C" void kernel_launch(void* const* d_in, const int* in_sizes, int n_in,
                              void* d_out, int out_size, void* d_ws, size_t ws_size,
                              hipStream_t stream) {
    (void)in_sizes; (void)n_in; (void)out_size; (void)ws_size;
    const float* pos   = (const float*)d_in[0];
    const float* feats = (const float*)d_in[1];
    const float* W1    = (const float*)d_in[2];
    const float* b1    = (const float*)d_in[3];
    const float* ln_g  = (const float*)d_in[4];
    const float* ln_b  = (const float*)d_in[5];
    const float* W2    = (const float*)d_in[6];
    const float* b2    = (const float*)d_in[7];
    const int*   ax1   = (const int*)d_in[8];
    const int*   ax2   = (const int*)d_in[9];

    float* out = (float*)d_out;          // accumulates sums in [COUT][NCELL]
    float* cnt = (float*)d_ws;           // [NCELL] counts (256 KB of ws)

    hipMemsetAsync(d_out, 0, (size_t)COUT * NCELL * sizeof(float), stream);
    hipMemsetAsync(d_ws, 0, (size_t)NCELL * sizeof(float), stream);

    point_kernel<<<PT_BLOCKS, PT_THREADS, 0, stream>>>(
        pos, feats, W1, b1, ln_g, ln_b, W2, b2, ax1, ax2, out, cnt);

    finalize_kernel<<<(COUT * NCELL) / 256, 256, 0, stream>>>(out, cnt);
}

// Round 4
// 525.365 us; speedup vs baseline: 3.6744x; 3.6744x over previous
//
#include <hip/hip_runtime.h>
#include <math.h>

// Problem constants (reference file)
#define NPTS   500000
#define CIN    16
#define COUT   64
#define PE     32
#define GRID_H 256
#define GRID_W 256
#define NCELL  (GRID_H * GRID_W)   // 65536

#define NK2_1    104                 // 208 rows of W1 -> 104 k-pairs
#define NK2_2    32                  // 64 rows of W2  -> 32 k-pairs
#define W1_HALF2 (NK2_1 * COUT)      // 6656 half2
#define W2_HALF2 (NK2_2 * COUT)      // 2048 half2
#define W_HALF2  (W1_HALF2 + W2_HALF2)   // 8704 half2 = 34816 B

// ws layout (bytes)
#define WS_HIST   0                      // 65536 u32  (256 KB)
#define WS_OFFS   262144                 // 65536 u32  (256 KB)
#define WS_SORT   524288                 // 500000 i32 (2 MB)
#define WS_WPK    2524288                // 8704 half2 (34816 B), 16-aligned

#define PT_BLOCKS ((NPTS + 255) / 256)   // 1954

typedef _Float16 h2v __attribute__((ext_vector_type(2)));
typedef _Float16 h8v __attribute__((ext_vector_type(8)));

#if __has_builtin(__builtin_amdgcn_fdot2)
#define FDOT2(a, b, c) __builtin_amdgcn_fdot2((a), (b), (c), false)
#else
__device__ __forceinline__ float FDOT2(h2v a, h2v b, float c) {
    return c + (float)a[0] * (float)b[0] + (float)a[1] * (float)b[1];
}
#endif

// One k-pair row (64 ch, 128 halfs = 256 B) from LDS, uniform address ->
// 16 broadcast ds_read_b128, accumulated into acc[0..63] (fp32) via dot2.
#define DOT_ROW(half_off, xp, acc)                                  \
    {                                                               \
        const h8v* row_ = (const h8v*)(Wl + (half_off));            \
        _Pragma("unroll")                                           \
        for (int r_ = 0; r_ < 16; ++r_) {                           \
            h8v w_ = row_[r_];                                      \
            h2v wA_; wA_[0] = w_[0]; wA_[1] = w_[1];                \
            h2v wB_; wB_[0] = w_[2]; wB_[1] = w_[3];                \
            h2v wC_; wC_[0] = w_[4]; wC_[1] = w_[5];                \
            h2v wD_; wD_[0] = w_[6]; wD_[1] = w_[7];                \
            acc[4 * r_ + 0] = FDOT2(xp, wA_, acc[4 * r_ + 0]);      \
            acc[4 * r_ + 1] = FDOT2(xp, wB_, acc[4 * r_ + 1]);      \
            acc[4 * r_ + 2] = FDOT2(xp, wC_, acc[4 * r_ + 2]);      \
            acc[4 * r_ + 3] = FDOT2(xp, wD_, acc[4 * r_ + 3]);      \
        }                                                           \
    }

__device__ __forceinline__ int cell_index(float v) {
    float nf = fminf(fmaxf((v + 1.0f) * 0.5f, 0.0f), 1.0f);
    int i = (int)floorf(nf * 256.0f);
    return i > 255 ? 255 : i;
}

__device__ __forceinline__ int flat_of(const float* pos, int p, int a1, int a2) {
    float pa1 = pos[p * 3 + a1];
    float pa2 = pos[p * 3 + a2];
    return cell_index(pa1) * GRID_W + cell_index(pa2);
}

// K0: pack W1|W2 as fp16 k-pair half2 into ws
__global__ void pack_w_kernel(const float* __restrict__ W1,
                              const float* __restrict__ W2,
                              h2v* __restrict__ wpk)
{
    int i = blockIdx.x * 256 + threadIdx.x;
    if (i >= W_HALF2) return;
    float a, b;
    if (i < W1_HALF2) {
        int base = ((i >> 6) << 7) | (i & 63);   // k2*128 + c
        a = W1[base]; b = W1[base + 64];
    } else {
        int j = i - W1_HALF2;
        int base = ((j >> 6) << 7) | (j & 63);
        a = W2[base]; b = W2[base + 64];
    }
    h2v p; p[0] = (_Float16)a; p[1] = (_Float16)b;
    wpk[i] = p;
}

// K1: histogram of cells
__global__ void hist_kernel(const float* __restrict__ pos,
                            const int* __restrict__ ax1p,
                            const int* __restrict__ ax2p,
                            unsigned int* __restrict__ hist)
{
    int p = blockIdx.x * 256 + threadIdx.x;
    if (p >= NPTS) return;
    atomicAdd(&hist[flat_of(pos, p, ax1p[0], ax2p[0])], 1u);
}

// K2: exclusive scan of hist[65536] -> offs (single block, 256 threads)
__global__ void scan_kernel(const unsigned int* __restrict__ hist,
                            unsigned int* __restrict__ offs)
{
    __shared__ unsigned int sc[256];
    const int t = threadIdx.x;
    const int base = t * 256;
    unsigned int s = 0;
    for (int i = 0; i < 256; ++i) s += hist[base + i];
    sc[t] = s;
    __syncthreads();
    for (int off = 1; off < 256; off <<= 1) {
        unsigned int add = (t >= off) ? sc[t - off] : 0u;
        __syncthreads();
        sc[t] += add;
        __syncthreads();
    }
    unsigned int run = sc[t] - s;          // exclusive prefix of this chunk
    for (int i = 0; i < 256; ++i) {
        offs[base + i] = run;
        run += hist[base + i];
    }
}

// K3: scatter point ids into sorted order (offs mutated into running cursors)
__global__ void scatter_kernel(const float* __restrict__ pos,
                               const int* __restrict__ ax1p,
                               const int* __restrict__ ax2p,
                               unsigned int* __restrict__ offs,
                               int* __restrict__ sorted)
{
    int p = blockIdx.x * 256 + threadIdx.x;
    if (p >= NPTS) return;
    int flat = flat_of(pos, p, ax1p[0], ax2p[0]);
    unsigned int dst = atomicAdd(&offs[flat], 1u);
    sorted[dst] = p;
}

// K4: MLP + per-wave segmented reduction + few atomics
__global__ __launch_bounds__(256)
void mlp_reduce_kernel(const float* __restrict__ pos,
                       const float* __restrict__ feats,
                       const h2v*  __restrict__ wpk,
                       const float* __restrict__ b1,
                       const float* __restrict__ ln_g,
                       const float* __restrict__ ln_b,
                       const float* __restrict__ b2,
                       const int*   __restrict__ ax1p,
                       const int*   __restrict__ ax2p,
                       const int*   __restrict__ sorted,
                       float* __restrict__ outSums)   // [COUT][NCELL] == d_out
{
    __shared__ __align__(16) _Float16 Wl[W_HALF2 * 2];   // 34816 B
    __shared__ _Float16 ldsH[256 * 66];                  // 33792 B, stride 66
    __shared__ int      ldsC[256];                       // 1 KB

    // stage packed weights (coalesced 16B copies)
    {
        const uint4* src = (const uint4*)wpk;
        uint4* dst = (uint4*)Wl;
        for (int i = threadIdx.x; i < W_HALF2 / 4; i += 256) dst[i] = src[i];
    }

    const int slot   = blockIdx.x * 256 + threadIdx.x;
    const bool valid = (slot < NPTS);
    const int p      = valid ? sorted[slot] : 0;

    const float px = pos[p * 3 + 0];
    const float py = pos[p * 3 + 1];
    const float pz = pos[p * 3 + 2];

    const int a1 = ax1p[0], a2 = ax2p[0];
    {
        float pa1 = (a1 == 0) ? px : ((a1 == 1) ? py : pz);
        float pa2 = (a2 == 0) ? px : ((a2 == 1) ? py : pz);
        int flat = cell_index(pa1) * GRID_W + cell_index(pa2);
        ldsC[threadIdx.x] = valid ? flat : 0x7FFFFFFF;
    }

    const float4* fvp = (const float4*)(feats + (size_t)p * CIN);
    const float4 f0 = fvp[0], f1 = fvp[1], f2 = fvp[2], f3 = fvp[3];

    __syncthreads();   // Wl + ldsC visible

    // ---- GEMM1: h = [feats | PE(pos)] @ W1 + b1 ---------------------------
    float h[COUT];
    #pragma unroll
    for (int c = 0; c < COUT; ++c) h[c] = b1[c];

    {
        h2v xp;
        xp[0] = (_Float16)f0.x; xp[1] = (_Float16)f0.y; DOT_ROW(0 * 128, xp, h);
        xp[0] = (_Float16)f0.z; xp[1] = (_Float16)f0.w; DOT_ROW(1 * 128, xp, h);
        xp[0] = (_Float16)f1.x; xp[1] = (_Float16)f1.y; DOT_ROW(2 * 128, xp, h);
        xp[0] = (_Float16)f1.z; xp[1] = (_Float16)f1.w; DOT_ROW(3 * 128, xp, h);
        xp[0] = (_Float16)f2.x; xp[1] = (_Float16)f2.y; DOT_ROW(4 * 128, xp, h);
        xp[0] = (_Float16)f2.z; xp[1] = (_Float16)f2.w; DOT_ROW(5 * 128, xp, h);
        xp[0] = (_Float16)f3.x; xp[1] = (_Float16)f3.y; DOT_ROW(6 * 128, xp, h);
        xp[0] = (_Float16)f3.z; xp[1] = (_Float16)f3.w; DOT_ROW(7 * 128, xp, h);
    }

    // PE rows: dim d -> sin k-pairs at k2=8+32d+j, cos at +16
    #pragma unroll 1
    for (int d = 0; d < 3; ++d) {
        float pv = (d == 0) ? px : ((d == 1) ? py : pz);
        int  k2b = 8 + 32 * d;
        float a  = pv * 1.57079632679489662f;
        #pragma unroll 1
        for (int j = 0; j < 16; ++j) {
            float s0 = __sinf(a);
            float s1 = __sinf(a * 1.0218971486541166f);
            h2v xp; xp[0] = (_Float16)s0; xp[1] = (_Float16)s1;
            DOT_ROW((k2b + j) * 128, xp, h);
            a *= 1.0442737824274138f;   // 2^(1/16)
        }
        a = pv * 1.57079632679489662f;
        #pragma unroll 1
        for (int j = 0; j < 16; ++j) {
            float c0 = __cosf(a);
            float c1 = __cosf(a * 1.0218971486541166f);
            h2v xp; xp[0] = (_Float16)c0; xp[1] = (_Float16)c1;
            DOT_ROW((k2b + 16 + j) * 128, xp, h);
            a *= 1.0442737824274138f;
        }
    }

    // ---- LayerNorm --------------------------------------------------------
    float s1 = 0.0f, s2 = 0.0f;
    #pragma unroll
    for (int c = 0; c < COUT; ++c) { s1 += h[c]; s2 += h[c] * h[c]; }
    float mu   = s1 * (1.0f / COUT);
    float var  = s2 * (1.0f / COUT) - mu * mu;
    float rstd = __builtin_amdgcn_rsqf(var + 1e-5f);

    // ---- GELU -> packed fp16 pairs ---------------------------------------
    h2v gh[NK2_2];
    #pragma unroll
    for (int c2 = 0; c2 < NK2_2; ++c2) {
        float xa = (h[2 * c2]     - mu) * rstd * ln_g[2 * c2]     + ln_b[2 * c2];
        float xb = (h[2 * c2 + 1] - mu) * rstd * ln_g[2 * c2 + 1] + ln_b[2 * c2 + 1];
        float ua = xa * (0.7978845608028654f + 0.0356774081363001f * xa * xa);
        float ub = xb * (0.7978845608028654f + 0.0356774081363001f * xb * xb);
        float ea = __expf(2.0f * ua);
        float eb = __expf(2.0f * ub);
        float ta = 1.0f - 2.0f * __builtin_amdgcn_rcpf(ea + 1.0f);
        float tb = 1.0f - 2.0f * __builtin_amdgcn_rcpf(eb + 1.0f);
        h2v g2;
        g2[0] = (_Float16)(0.5f * xa * (1.0f + ta));
        g2[1] = (_Float16)(0.5f * xb * (1.0f + tb));
        gh[c2] = g2;
    }

    // ---- GEMM2: fo = g @ W2 + b2 ------------------------------------------
    float fo[COUT];
    #pragma unroll
    for (int c = 0; c < COUT; ++c) fo[c] = b2[c];
    #pragma unroll
    for (int j2 = 0; j2 < NK2_2; ++j2) {
        DOT_ROW(W1_HALF2 * 2 + j2 * 128, gh[j2], fo);
    }

    // ---- stage fo to LDS as fp16, stride 66 halfs (conflict-free) --------
    {
        h2v* row = (h2v*)(ldsH + threadIdx.x * 66);
        #pragma unroll
        for (int c2 = 0; c2 < 32; ++c2) {
            h2v g; g[0] = (_Float16)fo[2 * c2]; g[1] = (_Float16)fo[2 * c2 + 1];
            row[c2] = g;
        }
    }
    __syncthreads();

    // ---- per-wave segmented reduction, one atomic per (run, channel) -----
    const int lane  = threadIdx.x & 63;
    const int wbase = threadIdx.x - lane;

    int myc = ldsC[wbase + lane];
    int prevc = __shfl_up(myc, 1);
    unsigned long long heads = __ballot(lane == 0 || myc != prevc);

    int s = 0;
    while (s < 64) {
        unsigned long long m = (heads >> s) >> 1;   // bits after s (safe for s=63)
        int e = m ? (s + __ffsll(m)) : 64;
        int c = __shfl(myc, s);
        if (c != 0x7FFFFFFF) {
            float sum = 0.0f;
            for (int i = s; i < e; ++i)
                sum += (float)ldsH[(wbase + i) * 66 + lane];
            unsafeAtomicAdd(&outSums[lane * NCELL + c], sum);
        }
        s = e;
    }
}

// K5: divide by counts, in place on d_out
__global__ void finalize_kernel(float* __restrict__ out,
                                const unsigned int* __restrict__ hist)
{
    int t = blockIdx.x * 256 + threadIdx.x;   // grid sized exactly 64*NCELL/256
    float c = (float)hist[t & (NCELL - 1)];
    out[t] = out[t] / fmaxf(c, 1.0f);
}

extern "C" void kernel_launch(void* const* d_in, const int* in_sizes, int n_in,
                              void* d_out, int out_size, void* d_ws, size_t ws_size,
                              hipStream_t stream) {
    (void)in_sizes; (void)n_in; (void)out_size; (void)ws_size;
    const float* pos   = (const float*)d_in[0];
    const float* feats = (const float*)d_in[1];
    const float* W1    = (const float*)d_in[2];
    const float* b1    = (const float*)d_in[3];
    const float* ln_g  = (const float*)d_in[4];
    const float* ln_b  = (const float*)d_in[5];
    const float* W2    = (const float*)d_in[6];
    const float* b2    = (const float*)d_in[7];
    const int*   ax1   = (const int*)d_in[8];
    const int*   ax2   = (const int*)d_in[9];

    char* ws = (char*)d_ws;
    unsigned int* hist = (unsigned int*)(ws + WS_HIST);
    unsigned int* offs = (unsigned int*)(ws + WS_OFFS);
    int*          sorted = (int*)(ws + WS_SORT);
    h2v*          wpk  = (h2v*)(ws + WS_WPK);

    float* out = (float*)d_out;   // accumulates sums in [COUT][NCELL]

    hipMemsetAsync(d_out, 0, (size_t)COUT * NCELL * sizeof(float), stream);
    hipMemsetAsync(hist, 0, NCELL * sizeof(unsigned int), stream);

    pack_w_kernel<<<(W_HALF2 + 255) / 256, 256, 0, stream>>>(W1, W2, wpk);
    hist_kernel<<<PT_BLOCKS, 256, 0, stream>>>(pos, ax1, ax2, hist);
    scan_kernel<<<1, 256, 0, stream>>>(hist, offs);
    scatter_kernel<<<PT_BLOCKS, 256, 0, stream>>>(pos, ax1, ax2, offs, sorted);
    mlp_reduce_kernel<<<PT_BLOCKS, 256, 0, stream>>>(
        pos, feats, wpk, b1, ln_g, ln_b, b2, ax1, ax2, sorted, out);
    finalize_kernel<<<(COUT * NCELL) / 256, 256, 0, stream>>>(out, hist);
}

// Round 6
// 432.729 us; speedup vs baseline: 4.4610x; 1.2141x over previous
//
#include <hip/hip_runtime.h>
#include <math.h>

// Problem constants (reference file)
#define NPTS   500000
#define CIN    16
#define COUT   64
#define PE     32
#define GRID_H 256
#define GRID_W 256
#define NCELL  (GRID_H * GRID_W)   // 65536

// ws layout (bytes)
#define WS_HIST   0                      // 65536 u32  (256 KB)
#define WS_OFFS   262144                 // 65536 u32  (256 KB)
#define WS_SORT   524288                 // 500000 i32 (2 MB)
#define WS_WPK    2524288                // 18432 f16 frag-packed weights (36864 B)

#define PT_BLOCKS ((NPTS + 255) / 256)   // 1954

#define W_HALFS   18432                  // (7+2)*4 frags * 64 lanes * 8 halfs
#define W1_FRAGS  28                     // 7 k-steps * 4 ch-tiles
#define H_STRIDE  72                     // halfs per point-row (144 B, 16B-aligned)
#define HW_HALFS  (64 * H_STRIDE)        // per-wave H buffer

typedef _Float16 f16x8 __attribute__((ext_vector_type(8)));
typedef float    f32x4 __attribute__((ext_vector_type(4)));

__device__ __forceinline__ int cell_index(float v) {
    float nf = fminf(fmaxf((v + 1.0f) * 0.5f, 0.0f), 1.0f);
    int i = (int)floorf(nf * 256.0f);
    return i > 255 ? 255 : i;
}

__device__ __forceinline__ int flat_of(const float* pos, int p, int a1, int a2) {
    float pa1 = pos[p * 3 + a1];
    float pa2 = pos[p * 3 + a2];
    return cell_index(pa1) * GRID_W + cell_index(pa2);
}

// K0: pack W1|W2 fp16 in MFMA B-fragment order.
// B-frag (16x16x32): lane holds B[k][n], n = lane&15, k = (lane>>4)*8 + j.
// layout: wpk[((frag)*64 + lane)*8 + j]; frag = s*4+c for W1 (s<7), 28+s*4+c for W2.
__global__ void pack_w_kernel(const float* __restrict__ W1,
                              const float* __restrict__ W2,
                              _Float16* __restrict__ wpk)
{
    int i = blockIdx.x * 256 + threadIdx.x;
    if (i >= W_HALFS) return;
    int j = i & 7, lane = (i >> 3) & 63, f = i >> 9;
    int k  = ((f < W1_FRAGS) ? (f >> 2) : ((f - W1_FRAGS) >> 2)) * 32 + ((lane >> 4) << 3) + j;
    int ch = (f & 3) * 16 + (lane & 15);
    float v;
    if (f < W1_FRAGS) v = (k < 208) ? W1[k * 64 + ch] : 0.0f;
    else              v = W2[k * 64 + ch];
    wpk[i] = (_Float16)v;
}

// K1: histogram of cells
__global__ void hist_kernel(const float* __restrict__ pos,
                            const int* __restrict__ ax1p,
                            const int* __restrict__ ax2p,
                            unsigned int* __restrict__ hist)
{
    int p = blockIdx.x * 256 + threadIdx.x;
    if (p >= NPTS) return;
    atomicAdd(&hist[flat_of(pos, p, ax1p[0], ax2p[0])], 1u);
}

// K2: exclusive scan of hist[65536] -> offs (single block, 1024 threads)
__global__ void scan_kernel(const unsigned int* __restrict__ hist,
                            unsigned int* __restrict__ offs)
{
    __shared__ unsigned int sc[1024];
    const int t = threadIdx.x;
    const int base = t * 64;
    unsigned int s = 0;
    for (int i = 0; i < 64; ++i) s += hist[base + i];
    sc[t] = s;
    __syncthreads();
    for (int off = 1; off < 1024; off <<= 1) {
        unsigned int add = (t >= off) ? sc[t - off] : 0u;
        __syncthreads();
        sc[t] += add;
        __syncthreads();
    }
    unsigned int run = sc[t] - s;          // exclusive prefix of this chunk
    for (int i = 0; i < 64; ++i) {
        offs[base + i] = run;
        run += hist[base + i];
    }
}

// K3: scatter point ids into sorted order (offs mutated into running cursors)
__global__ void scatter_kernel(const float* __restrict__ pos,
                               const int* __restrict__ ax1p,
                               const int* __restrict__ ax2p,
                               unsigned int* __restrict__ offs,
                               int* __restrict__ sorted)
{
    int p = blockIdx.x * 256 + threadIdx.x;
    if (p >= NPTS) return;
    int flat = flat_of(pos, p, ax1p[0], ax2p[0]);
    unsigned int dst = atomicAdd(&offs[flat], 1u);
    sorted[dst] = p;
}

// K4: MFMA MLP + per-wave segmented reduction.
// Wave handles 64 points (4 row-tiles of 16). A-frags built in registers,
// B-frags read lane-linear from frag-order LDS. LN via 16-lane xor-shuffle.
__global__ __launch_bounds__(256)
void mlp_mfma_kernel(const float* __restrict__ pos,
                     const float* __restrict__ feats,
                     const _Float16* __restrict__ wpk,
                     const float* __restrict__ b1,
                     const float* __restrict__ ln_g,
                     const float* __restrict__ ln_b,
                     const float* __restrict__ b2,
                     const int*   __restrict__ ax1p,
                     const int*   __restrict__ ax2p,
                     const int*   __restrict__ sorted,
                     float* __restrict__ outSums)   // [COUT][NCELL] == d_out
{
    __shared__ __align__(16) _Float16 WF[W_HALFS];        // 36864 B
    __shared__ __align__(16) _Float16 HB[4 * HW_HALFS];   // 36864 B (per-wave)
    __shared__ int ldsC[256];

    // stage frag-packed weights (coalesced 16B copies)
    {
        const uint4* src = (const uint4*)wpk;
        uint4* dst = (uint4*)WF;
        for (int i = threadIdx.x; i < W_HALFS / 8; i += 256) dst[i] = src[i];
    }

    const int slot   = blockIdx.x * 256 + threadIdx.x;
    const bool valid = (slot < NPTS);
    const int a1 = ax1p[0], a2 = ax2p[0];
    {
        int p0 = valid ? sorted[slot] : 0;
        ldsC[threadIdx.x] = valid ? flat_of(pos, p0, a1, a2) : 0x7FFFFFFF;
    }
    __syncthreads();

    const int lane = threadIdx.x & 63;
    const int wv   = threadIdx.x >> 6;
    const int g    = lane >> 4;        // quad
    const int n    = lane & 15;
    _Float16* Hw = HB + wv * HW_HALFS;

    // per-channel params for ch = n + 16c
    float b1v[4], b2v[4], lgv[4], lbv[4];
    #pragma unroll
    for (int c = 0; c < 4; ++c) {
        int ch = n + 16 * c;
        b1v[c] = b1[ch]; b2v[c] = b2[ch]; lgv[c] = ln_g[ch]; lbv[c] = ln_b[ch];
    }

    // per-tile point data: lane serves point (t*16 + n)
    int   pt[4];
    float ppx[4], ppy[4], ppz[4];
    #pragma unroll
    for (int t = 0; t < 4; ++t) {
        int st = blockIdx.x * 256 + wv * 64 + t * 16 + n;
        int p  = (st < NPTS) ? sorted[st] : 0;
        pt[t]  = p;
        ppx[t] = pos[3 * p + 0];
        ppy[t] = pos[3 * p + 1];
        ppz[t] = pos[3 * p + 2];
    }

    // ---- GEMM1: acc[t][c] (16 pts x 16 ch), K = 224 (208 + zero pad) ------
    f32x4 acc[4][4];
    #pragma unroll
    for (int t = 0; t < 4; ++t)
        #pragma unroll
        for (int c = 0; c < 4; ++c)
            acc[t][c] = (f32x4){0.0f, 0.0f, 0.0f, 0.0f};

    const int kb = /* s*32 + */ g * 8;   // per-lane k base within step
    #pragma unroll
    for (int s = 0; s < 7; ++s) {
        f16x8 af[4];
        #pragma unroll
        for (int t = 0; t < 4; ++t) {
            int k0 = s * 32 + kb;
            f16x8 a;
            if (k0 < 16) {                       // feats rows (s==0, g<2)
                const float4* fr = (const float4*)(feats + (size_t)pt[t] * CIN + k0);
                float4 u0 = fr[0], u1 = fr[1];
                a[0] = (_Float16)u0.x; a[1] = (_Float16)u0.y;
                a[2] = (_Float16)u0.z; a[3] = (_Float16)u0.w;
                a[4] = (_Float16)u1.x; a[5] = (_Float16)u1.y;
                a[6] = (_Float16)u1.z; a[7] = (_Float16)u1.w;
            } else if (k0 >= 208) {              // zero pad (s==6, g>=2)
                #pragma unroll
                for (int j = 0; j < 8; ++j) a[j] = (_Float16)0.0f;
            } else {                             // PE: e = k0-16 = d*64+sc*32+f0
                int e  = k0 - 16;
                int d  = e >> 6;
                int sc = (e >> 5) & 1;
                int f0 = e & 31;
                float pv  = (d == 0) ? ppx[t] : ((d == 1) ? ppy[t] : ppz[t]);
                float ang = pv * 1.57079632679489662f * exp2f((float)f0 * 0.03125f);
                #pragma unroll
                for (int j = 0; j < 8; ++j) {
                    float v = sc ? __cosf(ang) : __sinf(ang);
                    a[j] = (_Float16)v;
                    ang *= 1.02189714865411668f;   // 2^(1/32)
                }
            }
            af[t] = a;
        }
        #pragma unroll
        for (int c = 0; c < 4; ++c) {
            f16x8 bf = ((const f16x8*)WF)[(s * 4 + c) * 64 + lane];
            #pragma unroll
            for (int t = 0; t < 4; ++t)
                acc[t][c] = __builtin_amdgcn_mfma_f32_16x16x32_f16(af[t], bf, acc[t][c], 0, 0, 0);
        }
    }

    // ---- bias + LayerNorm + GELU -> P (fp16) in per-wave LDS --------------
    // D layout: lane holds D[row = 4g + r][ch = n + 16c], r = 0..3
    #pragma unroll
    for (int t = 0; t < 4; ++t) {
        f32x4 s1 = (f32x4){0.0f, 0.0f, 0.0f, 0.0f};
        f32x4 s2 = (f32x4){0.0f, 0.0f, 0.0f, 0.0f};
        #pragma unroll
        for (int c = 0; c < 4; ++c) {
            #pragma unroll
            for (int r = 0; r < 4; ++r) {
                float x = acc[t][c][r] + b1v[c];
                acc[t][c][r] = x;
                s1[r] += x;
                s2[r] += x * x;
            }
        }
        #pragma unroll
        for (int m = 1; m <= 8; m <<= 1) {
            #pragma unroll
            for (int r = 0; r < 4; ++r) {
                s1[r] += __shfl_xor(s1[r], m);
                s2[r] += __shfl_xor(s2[r], m);
            }
        }
        #pragma unroll
        for (int r = 0; r < 4; ++r) {
            float mu   = s1[r] * (1.0f / 64.0f);
            float var  = s2[r] * (1.0f / 64.0f) - mu * mu;
            float rstd = __builtin_amdgcn_rsqf(var + 1e-5f);
            int row = t * 16 + 4 * g + r;
            #pragma unroll
            for (int c = 0; c < 4; ++c) {
                float x  = (acc[t][c][r] - mu) * rstd * lgv[c] + lbv[c];
                float u  = x * (0.7978845608028654f + 0.0356774081363001f * x * x);
                float e  = __expf(2.0f * u);
                float th = 1.0f - 2.0f * __builtin_amdgcn_rcpf(e + 1.0f);
                float gv = 0.5f * x * (1.0f + th);
                Hw[row * H_STRIDE + n + 16 * c] = (_Float16)gv;
            }
        }
    }
    __syncthreads();   // wave-local buffer, but keep ordering safe vs reads below

    // ---- GEMM2: pre-read all A2 frags, then overwrite H with D2 -----------
    f16x8 a2f[4][2];
    #pragma unroll
    for (int t = 0; t < 4; ++t)
        #pragma unroll
        for (int s = 0; s < 2; ++s)
            a2f[t][s] = *(const f16x8*)(Hw + (t * 16 + n) * H_STRIDE + s * 32 + g * 8);

    #pragma unroll
    for (int t = 0; t < 4; ++t) {
        f32x4 acc2[4];
        #pragma unroll
        for (int c = 0; c < 4; ++c) acc2[c] = (f32x4){0.0f, 0.0f, 0.0f, 0.0f};
        #pragma unroll
        for (int s = 0; s < 2; ++s) {
            #pragma unroll
            for (int c = 0; c < 4; ++c) {
                f16x8 bf = ((const f16x8*)WF)[(W1_FRAGS + s * 4 + c) * 64 + lane];
                acc2[c] = __builtin_amdgcn_mfma_f32_16x16x32_f16(a2f[t][s], bf, acc2[c], 0, 0, 0);
            }
        }
        #pragma unroll
        for (int r = 0; r < 4; ++r) {
            int row = t * 16 + 4 * g + r;
            #pragma unroll
            for (int c = 0; c < 4; ++c)
                Hw[row * H_STRIDE + n + 16 * c] = (_Float16)(acc2[c][r] + b2v[c]);
        }
    }

    // ---- per-wave segmented reduction, one atomic per (run, channel) ------
    int myc = ldsC[threadIdx.x];
    int prevc = __shfl_up(myc, 1);
    unsigned long long heads = __ballot(lane == 0 || myc != prevc);

    int s = 0;
    while (s < 64) {
        unsigned long long m = (heads >> s) >> 1;   // bits after s (safe for s=63)
        int e = m ? (s + __ffsll(m)) : 64;
        int c = __shfl(myc, s);
        if (c != 0x7FFFFFFF) {
            float sum = 0.0f;
            for (int i = s; i < e; ++i)
                sum += (float)Hw[i * H_STRIDE + lane];
            unsafeAtomicAdd(&outSums[lane * NCELL + c], sum);
        }
        s = e;
    }
}

// K5: divide by counts, in place on d_out
__global__ void finalize_kernel(float* __restrict__ out,
                                const unsigned int* __restrict__ hist)
{
    int t = blockIdx.x * 256 + threadIdx.x;   // grid sized exactly 64*NCELL/256
    float c = (float)hist[t & (NCELL - 1)];
    out[t] = out[t] / fmaxf(c, 1.0f);
}

extern "C" void kernel_launch(void* const* d_in, const int* in_sizes, int n_in,
                              void* d_out, int out_size, void* d_ws, size_t ws_size,
                              hipStream_t stream) {
    (void)in_sizes; (void)n_in; (void)out_size; (void)ws_size;
    const float* pos   = (const float*)d_in[0];
    const float* feats = (const float*)d_in[1];
    const float* W1    = (const float*)d_in[2];
    const float* b1    = (const float*)d_in[3];
    const float* ln_g  = (const float*)d_in[4];
    const float* ln_b  = (const float*)d_in[5];
    const float* W2    = (const float*)d_in[6];
    const float* b2    = (const float*)d_in[7];
    const int*   ax1   = (const int*)d_in[8];
    const int*   ax2   = (const int*)d_in[9];

    char* ws = (char*)d_ws;
    unsigned int* hist   = (unsigned int*)(ws + WS_HIST);
    unsigned int* offs   = (unsigned int*)(ws + WS_OFFS);
    int*          sorted = (int*)(ws + WS_SORT);
    _Float16*     wpk    = (_Float16*)(ws + WS_WPK);

    float* out = (float*)d_out;   // accumulates sums in [COUT][NCELL]

    hipMemsetAsync(d_out, 0, (size_t)COUT * NCELL * sizeof(float), stream);
    hipMemsetAsync(hist, 0, NCELL * sizeof(unsigned int), stream);

    pack_w_kernel<<<W_HALFS / 256, 256, 0, stream>>>(W1, W2, wpk);
    hist_kernel<<<PT_BLOCKS, 256, 0, stream>>>(pos, ax1, ax2, hist);
    scan_kernel<<<1, 1024, 0, stream>>>(hist, offs);
    scatter_kernel<<<PT_BLOCKS, 256, 0, stream>>>(pos, ax1, ax2, offs, sorted);
    mlp_mfma_kernel<<<PT_BLOCKS, 256, 0, stream>>>(
        pos, feats, wpk, b1, ln_g, ln_b, b2, ax1, ax2, sorted, out);
    finalize_kernel<<<(COUT * NCELL) / 256, 256, 0, stream>>>(out, hist);
}